// Round 3
// baseline (195.130 us; speedup 1.0000x reference)
//
#include <hip/hip_runtime.h>
#include <math.h>
#include <float.h>

// Problem constants (match reference)
#define BATCH 4
#define KCLS 16
#define NSRC 4096
#define NTGT 16384

// geometry: 256 threads = 4 waves; 8 targets/lane -> 512 targets/block.
// OCCUPANCY-FIRST: R0-R2 showed nn time tracks waves/SIMD (true VALU issue
// ~58% at <=45% occupancy). 256-thread blocks + 16 KB LDS + SPLITS=16 give
// grid=2048 -> 8 blocks/CU -> 8 waves/SIMD (the hardware max), filling the
// dependency-stall bubbles. TPL=8 keeps 64 VALU instrs per ds_read_b128 so
// the LDS pipe stays <40% even at full occupancy.
#define THREADS 256
#define WAVES 4
#define TPL 8                               // targets per lane
#define TGT_PER_BLOCK 512                   // 64 lanes * TPL (shared by all waves)

// ---------------------------------------------------------------------------
// nn_kernel<SPLITS>: per-(target, source-chunk) argmin partials, bit-exact
// numerics (verified absmax=0.0 chain):
//   ss/tt: squares rounded individually, then sequential sum
//   dot  : rn(tx*sx); fma(ty,sy,.); fma(tz,sz,.)
//   d2   : fma(-2, dot, rn(tt+ss))
// Sources staged in LDS, consumed as wave-uniform ds_read_b128 broadcasts.
// Epilogue: plain coalesced u64 store per (split, target) — no atomics.
// SPLITS=16 (8 MB partials) when ws allows, else SPLITS=8 (4 MB, R1-proven).
// ---------------------------------------------------------------------------
template <int SPLITS>
__global__ __launch_bounds__(THREADS, 8) void nn_kernel(
    const float* __restrict__ source_pos,   // [B, 3, NS]
    const float* __restrict__ target_pos,   // [B, 3, NT]
    unsigned long long* __restrict__ part)  // [B][SPLITS][NTGT]
{
    constexpr int CHUNK = NSRC / SPLITS;    // 256 (S=16) / 512 (S=8)
    constexpr int STRIPE = CHUNK / WAVES;   // 64 / 128 iterations per wave

    // 16 KB: stage uses first CHUNK float4s; aliased after the scan as
    // smin[4][512] (8 KB) | sidx[4][512] (8 KB).
    __shared__ float4 ls[1024];

    int tid = threadIdx.x;
    int lane = tid & 63;
    int wave = tid >> 6;                    // 0..3

    // grid decode: blocksPerBatch = 32 tgroups * SPLITS (split fastest so
    // adjacent blocks share target cachelines)
    constexpr int BPB = (NTGT / TGT_PER_BLOCK) * SPLITS;
    int b = blockIdx.x / BPB;
    int rem = blockIdx.x % BPB;
    int tg = rem / SPLITS;
    int split = rem % SPLITS;
    int tbase = tg * TGT_PER_BLOCK;
    int cg = split * CHUNK;                 // this block's source-chunk base

    // stage chunk (coalesced x/y/z streams), 1-2 sources per thread
    const float* sxp = source_pos + (size_t)b * 3 * NSRC;
    const float* syp = sxp + NSRC;
    const float* szp = sxp + 2 * NSRC;
#pragma unroll
    for (int r = 0; r < CHUNK / THREADS; ++r) {
        int s = r * THREADS + tid;
        float x = sxp[cg + s], y = syp[cg + s], z = szp[cg + s];
        float ss = __fadd_rn(__fadd_rn(__fmul_rn(x, x), __fmul_rn(y, y)),
                             __fmul_rn(z, z));
        ls[s] = make_float4(x, y, z, ss);
    }

    // eight targets per lane: t_j = tbase + 64*j + lane (coalesced loads;
    // every wave holds the full 512-target block)
    const float* tp = target_pos + (size_t)b * 3 * NTGT;
    float tx[TPL], ty[TPL], tz[TPL], tt[TPL];
#pragma unroll
    for (int j = 0; j < TPL; ++j) {
        int t = tbase + 64 * j + lane;
        tx[j] = tp[t]; ty[j] = tp[NTGT + t]; tz[j] = tp[2 * NTGT + t];
        tt[j] = __fadd_rn(__fadd_rn(__fmul_rn(tx[j], tx[j]),
                                    __fmul_rn(ty[j], ty[j])),
                          __fmul_rn(tz[j], tz[j]));
    }

    __syncthreads();

    int lbase = wave * STRIPE;              // this wave's stripe in the chunk
    int gbase = cg + lbase;                 // global source index base (uniform)
    float best[TPL];
    int bi[TPL];
#pragma unroll
    for (int j = 0; j < TPL; ++j) { best[j] = FLT_MAX; bi[j] = 0; }

#pragma unroll 8
    for (int i = 0; i < STRIPE; ++i) {
        float4 f = ls[lbase + i];           // wave-uniform -> LDS broadcast
        int cand = gbase + i;
#pragma unroll
        for (int j = 0; j < TPL; ++j) {
            float acc = __fmul_rn(tx[j], f.x);
            acc = __fmaf_rn(ty[j], f.y, acc);
            acc = __fmaf_rn(tz[j], f.z, acc);
            float d2 = __fmaf_rn(-2.0f, acc, __fadd_rn(tt[j], f.w));
            if (d2 < best[j]) { best[j] = d2; bi[j] = cand; }  // strict '<'
        }
    }

    __syncthreads();                        // done READING ls before aliasing

    // cross-wave combine in LDS (waves cover ascending source stripes, so
    // ascending-w scan with strict-less + tie->lower-index == np.argmin).
    float* smin = (float*)ls;
    int* sidx = (int*)(smin + WAVES * TGT_PER_BLOCK);
#pragma unroll
    for (int j = 0; j < TPL; ++j) {
        smin[wave * TGT_PER_BLOCK + 64 * j + lane] = best[j];
        sidx[wave * TGT_PER_BLOCK + 64 * j + lane] = bi[j];
    }
    __syncthreads();

#pragma unroll
    for (int r = 0; r < TGT_PER_BLOCK / THREADS; ++r) {
        int t = r * THREADS + tid;
        float m = smin[t];
        int mi = sidx[t];
#pragma unroll
        for (int w = 1; w < WAVES; ++w) {
            float mj = smin[w * TGT_PER_BLOCK + t];
            int ij = sidx[w * TGT_PER_BLOCK + t];
            if (mj < m || (mj == m && ij < mi)) { m = mj; mi = ij; }
        }
        // total-order map: monotone wrt float '<' (handles negatives); the
        // packed u64 compares lexicographically as (d2, first index).
        unsigned u = __float_as_uint(m);
        unsigned ord = (u & 0x80000000u) ? ~u : (u | 0x80000000u);
        part[((size_t)b * SPLITS + split) * NTGT + tbase + t] =
            ((unsigned long long)ord << 32) | (unsigned)mi;
    }
}

// ---------------------------------------------------------------------------
// gate_kernel<SPLITS>: combine split-partials (plain u64 '<' min ==
// lexicographic (d2, first-index), bit-identical winner across ascending
// splits), then the verified 16-way strided max over sem_logits + sigmoid.
// ---------------------------------------------------------------------------
template <int SPLITS>
__global__ __launch_bounds__(256) void gate_kernel(
    const unsigned long long* __restrict__ part,  // [B][SPLITS][NTGT]
    const float* __restrict__ sem_logits,         // [B, K, NS]
    float* __restrict__ out)                      // [B*NT]
{
    int gt = blockIdx.x * 256 + threadIdx.x;      // 0 .. B*NT-1
    int b = gt >> 14;                             // NTGT == 16384
    int t = gt & (NTGT - 1);

    const unsigned long long* pp = part + (size_t)b * SPLITS * NTGT + t;
    unsigned long long best = pp[0];
#pragma unroll
    for (int s = 1; s < SPLITS; ++s) {
        unsigned long long v = pp[(size_t)s * NTGT];  // coalesced in t
        if (v < best) best = v;
    }
    int mi = (int)(best & 0xFFFFFFFFull);

    const float* lg = sem_logits + (size_t)b * KCLS * NSRC + mi;
    float mm = lg[0];
#pragma unroll
    for (int k = 1; k < KCLS; ++k) mm = fmaxf(mm, lg[(size_t)k * NSRC]);
    out[gt] = 1.0f / (1.0f + expf(-mm));
}

extern "C" void kernel_launch(void* const* d_in, const int* in_sizes, int n_in,
                              void* d_out, int out_size, void* d_ws, size_t ws_size,
                              hipStream_t stream) {
    const float* sem_logits = (const float*)d_in[0];   // [B,K,NS] fp32
    const float* source_pos = (const float*)d_in[1];   // [B,3,NS] fp32
    const float* target_pos = (const float*)d_in[2];   // [B,3,NT] fp32
    float* out = (float*)d_out;                        // [B,NT,1] fp32

    unsigned long long* part = (unsigned long long*)d_ws;

    const size_t need16 = (size_t)BATCH * 16 * NTGT * 8;   // 8 MB
    if (ws_size >= need16) {
        nn_kernel<16><<<BATCH * (NTGT / TGT_PER_BLOCK) * 16, THREADS, 0, stream>>>(
            source_pos, target_pos, part);
        gate_kernel<16><<<(BATCH * NTGT) / 256, 256, 0, stream>>>(
            part, sem_logits, out);
    } else {
        // fallback: 4 MB partials (R1-proven workspace size)
        nn_kernel<8><<<BATCH * (NTGT / TGT_PER_BLOCK) * 8, THREADS, 0, stream>>>(
            source_pos, target_pos, part);
        gate_kernel<8><<<(BATCH * NTGT) / 256, 256, 0, stream>>>(
            part, sem_logits, out);
    }
}

// Round 4
// 104.066 us; speedup vs baseline: 1.8751x; 1.8751x over previous
//
#include <hip/hip_runtime.h>
#include <math.h>
#include <float.h>

// Problem constants (match reference)
#define BATCH 4
#define KCLS 16
#define NSRC 4096
#define NTGT 16384

// geometry: 256 threads = 4 waves; 8 targets/lane -> 512 targets/block.
// R3 post-mortem: the (256,8) launch bound capped VGPRs at 64 and the
// compiler SPILLED the per-lane target/best state to scratch (340 MB fetch +
// 218 MB write per dispatch, kernel became scratch-BW-bound). The geometry
// itself packed fine (occupancy 84%). Fix: NO min-waves clause — the loop
// body needs ~36-44 VGPRs naturally (R2 measured 36), which is <= 64, so HW
// occupancy reaches 8 blocks/CU (2048 thr, 128 KB LDS) without any cap.
#define THREADS 256
#define WAVES 4
#define TPL 8                               // targets per lane
#define TGT_PER_BLOCK 512                   // 64 lanes * TPL (shared by all waves)

// ---------------------------------------------------------------------------
// nn_kernel<SPLITS>: per-(target, source-chunk) argmin partials, bit-exact
// numerics (verified absmax=0.0 chain):
//   ss/tt: squares rounded individually, then sequential sum
//   dot  : rn(tx*sx); fma(ty,sy,.); fma(tz,sz,.)
//   d2   : fma(-2, dot, rn(tt+ss))
// Sources staged in LDS, consumed as wave-uniform ds_read_b128 broadcasts.
// Epilogue: plain coalesced u64 store per (split, target) — no atomics.
// SPLITS=16 (8 MB partials) when ws allows, else SPLITS=8 (4 MB, R1-proven).
// ---------------------------------------------------------------------------
template <int SPLITS>
__global__ __launch_bounds__(THREADS) void nn_kernel(
    const float* __restrict__ source_pos,   // [B, 3, NS]
    const float* __restrict__ target_pos,   // [B, 3, NT]
    unsigned long long* __restrict__ part)  // [B][SPLITS][NTGT]
{
    constexpr int CHUNK = NSRC / SPLITS;    // 256 (S=16) / 512 (S=8)
    constexpr int STRIPE = CHUNK / WAVES;   // 64 / 128 iterations per wave

    // 16 KB: stage uses first CHUNK float4s; aliased after the scan as
    // smin[4][512] (8 KB) | sidx[4][512] (8 KB).
    __shared__ float4 ls[1024];

    int tid = threadIdx.x;
    int lane = tid & 63;
    int wave = tid >> 6;                    // 0..3

    // grid decode: blocksPerBatch = 32 tgroups * SPLITS (split fastest so
    // adjacent blocks share target cachelines)
    constexpr int BPB = (NTGT / TGT_PER_BLOCK) * SPLITS;
    int b = blockIdx.x / BPB;
    int rem = blockIdx.x % BPB;
    int tg = rem / SPLITS;
    int split = rem % SPLITS;
    int tbase = tg * TGT_PER_BLOCK;
    int cg = split * CHUNK;                 // this block's source-chunk base

    // stage chunk (coalesced x/y/z streams), 1-2 sources per thread
    const float* sxp = source_pos + (size_t)b * 3 * NSRC;
    const float* syp = sxp + NSRC;
    const float* szp = sxp + 2 * NSRC;
#pragma unroll
    for (int r = 0; r < CHUNK / THREADS; ++r) {
        int s = r * THREADS + tid;
        float x = sxp[cg + s], y = syp[cg + s], z = szp[cg + s];
        float ss = __fadd_rn(__fadd_rn(__fmul_rn(x, x), __fmul_rn(y, y)),
                             __fmul_rn(z, z));
        ls[s] = make_float4(x, y, z, ss);
    }

    // eight targets per lane: t_j = tbase + 64*j + lane (coalesced loads;
    // every wave holds the full 512-target block)
    const float* tp = target_pos + (size_t)b * 3 * NTGT;
    float tx[TPL], ty[TPL], tz[TPL], tt[TPL];
#pragma unroll
    for (int j = 0; j < TPL; ++j) {
        int t = tbase + 64 * j + lane;
        tx[j] = tp[t]; ty[j] = tp[NTGT + t]; tz[j] = tp[2 * NTGT + t];
        tt[j] = __fadd_rn(__fadd_rn(__fmul_rn(tx[j], tx[j]),
                                    __fmul_rn(ty[j], ty[j])),
                          __fmul_rn(tz[j], tz[j]));
    }

    __syncthreads();

    int lbase = wave * STRIPE;              // this wave's stripe in the chunk
    int gbase = cg + lbase;                 // global source index base (uniform)
    float best[TPL];
    int bi[TPL];
#pragma unroll
    for (int j = 0; j < TPL; ++j) { best[j] = FLT_MAX; bi[j] = 0; }

#pragma unroll 8
    for (int i = 0; i < STRIPE; ++i) {
        float4 f = ls[lbase + i];           // wave-uniform -> LDS broadcast
        int cand = gbase + i;
#pragma unroll
        for (int j = 0; j < TPL; ++j) {
            float acc = __fmul_rn(tx[j], f.x);
            acc = __fmaf_rn(ty[j], f.y, acc);
            acc = __fmaf_rn(tz[j], f.z, acc);
            float d2 = __fmaf_rn(-2.0f, acc, __fadd_rn(tt[j], f.w));
            if (d2 < best[j]) { best[j] = d2; bi[j] = cand; }  // strict '<'
        }
    }

    __syncthreads();                        // done READING ls before aliasing

    // cross-wave combine in LDS (waves cover ascending source stripes, so
    // ascending-w scan with strict-less + tie->lower-index == np.argmin).
    float* smin = (float*)ls;
    int* sidx = (int*)(smin + WAVES * TGT_PER_BLOCK);
#pragma unroll
    for (int j = 0; j < TPL; ++j) {
        smin[wave * TGT_PER_BLOCK + 64 * j + lane] = best[j];
        sidx[wave * TGT_PER_BLOCK + 64 * j + lane] = bi[j];
    }
    __syncthreads();

#pragma unroll
    for (int r = 0; r < TGT_PER_BLOCK / THREADS; ++r) {
        int t = r * THREADS + tid;
        float m = smin[t];
        int mi = sidx[t];
#pragma unroll
        for (int w = 1; w < WAVES; ++w) {
            float mj = smin[w * TGT_PER_BLOCK + t];
            int ij = sidx[w * TGT_PER_BLOCK + t];
            if (mj < m || (mj == m && ij < mi)) { m = mj; mi = ij; }
        }
        // total-order map: monotone wrt float '<' (handles negatives); the
        // packed u64 compares lexicographically as (d2, first index).
        unsigned u = __float_as_uint(m);
        unsigned ord = (u & 0x80000000u) ? ~u : (u | 0x80000000u);
        part[((size_t)b * SPLITS + split) * NTGT + tbase + t] =
            ((unsigned long long)ord << 32) | (unsigned)mi;
    }
}

// ---------------------------------------------------------------------------
// gate_kernel<SPLITS>: combine split-partials (plain u64 '<' min ==
// lexicographic (d2, first-index), bit-identical winner across ascending
// splits), then the verified 16-way strided max over sem_logits + sigmoid.
// ---------------------------------------------------------------------------
template <int SPLITS>
__global__ __launch_bounds__(256) void gate_kernel(
    const unsigned long long* __restrict__ part,  // [B][SPLITS][NTGT]
    const float* __restrict__ sem_logits,         // [B, K, NS]
    float* __restrict__ out)                      // [B*NT]
{
    int gt = blockIdx.x * 256 + threadIdx.x;      // 0 .. B*NT-1
    int b = gt >> 14;                             // NTGT == 16384
    int t = gt & (NTGT - 1);

    const unsigned long long* pp = part + (size_t)b * SPLITS * NTGT + t;
    unsigned long long best = pp[0];
#pragma unroll
    for (int s = 1; s < SPLITS; ++s) {
        unsigned long long v = pp[(size_t)s * NTGT];  // coalesced in t
        if (v < best) best = v;
    }
    int mi = (int)(best & 0xFFFFFFFFull);

    const float* lg = sem_logits + (size_t)b * KCLS * NSRC + mi;
    float mm = lg[0];
#pragma unroll
    for (int k = 1; k < KCLS; ++k) mm = fmaxf(mm, lg[(size_t)k * NSRC]);
    out[gt] = 1.0f / (1.0f + expf(-mm));
}

extern "C" void kernel_launch(void* const* d_in, const int* in_sizes, int n_in,
                              void* d_out, int out_size, void* d_ws, size_t ws_size,
                              hipStream_t stream) {
    const float* sem_logits = (const float*)d_in[0];   // [B,K,NS] fp32
    const float* source_pos = (const float*)d_in[1];   // [B,3,NS] fp32
    const float* target_pos = (const float*)d_in[2];   // [B,3,NT] fp32
    float* out = (float*)d_out;                        // [B,NT,1] fp32

    unsigned long long* part = (unsigned long long*)d_ws;

    const size_t need16 = (size_t)BATCH * 16 * NTGT * 8;   // 8 MB
    if (ws_size >= need16) {
        nn_kernel<16><<<BATCH * (NTGT / TGT_PER_BLOCK) * 16, THREADS, 0, stream>>>(
            source_pos, target_pos, part);
        gate_kernel<16><<<(BATCH * NTGT) / 256, 256, 0, stream>>>(
            part, sem_logits, out);
    } else {
        // fallback: 4 MB partials (R1-proven workspace size)
        nn_kernel<8><<<BATCH * (NTGT / TGT_PER_BLOCK) * 8, THREADS, 0, stream>>>(
            source_pos, target_pos, part);
        gate_kernel<8><<<(BATCH * NTGT) / 256, 256, 0, stream>>>(
            part, sem_logits, out);
    }
}

// Round 6
// 101.793 us; speedup vs baseline: 1.9169x; 1.0223x over previous
//
#include <hip/hip_runtime.h>
#include <math.h>
#include <float.h>

// Problem constants (match reference)
#define BATCH 4
#define KCLS 16
#define NSRC 4096
#define NTGT 16384

// geometry: 256 threads = 4 waves; 8 targets/lane -> 512 targets/block;
// SPLITS=16 -> chunk=256 sources; grid = 4*32*16 = 2048 (R4-verified).
// R6 change: explicit cross-body software pipeline of the LDS source reads
// (cur/nxt register double-buffer, groups of 4) to remove the per-unroll-body
// lgkmcnt bubble the compiler does not schedule across the back-edge.
// Numerics, select semantics, combine, epilogue: byte-identical to R4
// (verified absmax=0.0).
#define THREADS 256
#define WAVES 4
#define TPL 8                               // targets per lane
#define TGT_PER_BLOCK 512                   // 64 lanes * TPL

// ---------------------------------------------------------------------------
// nn_kernel<SPLITS>: per-(target, source-chunk) argmin partials, bit-exact
// numerics (verified absmax=0.0 chain):
//   ss/tt: squares rounded individually, then sequential sum
//   dot  : rn(tx*sx); fma(ty,sy,.); fma(tz,sz,.)
//   d2   : fma(-2, dot, rn(tt+ss))
// Sources staged in LDS, consumed as wave-uniform ds_read_b128 broadcasts
// through a depth-1 register pipeline (4 float4s/group). Epilogue: plain
// coalesced u64 store per (split, target) — no atomics.
// ---------------------------------------------------------------------------
template <int SPLITS>
__global__ __launch_bounds__(THREADS) void nn_kernel(
    const float* __restrict__ source_pos,   // [B, 3, NS]
    const float* __restrict__ target_pos,   // [B, 3, NT]
    unsigned long long* __restrict__ part)  // [B][SPLITS][NTGT]
{
    constexpr int CHUNK = NSRC / SPLITS;    // 256 (S=16) / 512 (S=8)
    constexpr int STRIPE = CHUNK / WAVES;   // 64 / 128 iterations per wave

    // 16 KB: stage uses first CHUNK float4s; aliased after the scan as
    // smin[4][512] (8 KB) | sidx[4][512] (8 KB).
    __shared__ float4 ls[1024];

    int tid = threadIdx.x;
    int lane = tid & 63;
    int wave = tid >> 6;                    // 0..3

    // grid decode: blocksPerBatch = 32 tgroups * SPLITS (split fastest)
    constexpr int BPB = (NTGT / TGT_PER_BLOCK) * SPLITS;
    int b = blockIdx.x / BPB;
    int rem = blockIdx.x % BPB;
    int tg = rem / SPLITS;
    int split = rem % SPLITS;
    int tbase = tg * TGT_PER_BLOCK;
    int cg = split * CHUNK;                 // this block's source-chunk base

    // stage chunk (coalesced x/y/z streams), 1-2 sources per thread
    const float* sxp = source_pos + (size_t)b * 3 * NSRC;
    const float* syp = sxp + NSRC;
    const float* szp = sxp + 2 * NSRC;
#pragma unroll
    for (int r = 0; r < (CHUNK + THREADS - 1) / THREADS; ++r) {
        int s = r * THREADS + tid;
        if (s < CHUNK) {
            float x = sxp[cg + s], y = syp[cg + s], z = szp[cg + s];
            float ss = __fadd_rn(__fadd_rn(__fmul_rn(x, x), __fmul_rn(y, y)),
                                 __fmul_rn(z, z));
            ls[s] = make_float4(x, y, z, ss);
        }
    }

    // eight targets per lane: t_j = tbase + 64*j + lane (coalesced loads)
    const float* tp = target_pos + (size_t)b * 3 * NTGT;
    float tx[TPL], ty[TPL], tz[TPL], tt[TPL];
#pragma unroll
    for (int j = 0; j < TPL; ++j) {
        int t = tbase + 64 * j + lane;
        tx[j] = tp[t]; ty[j] = tp[NTGT + t]; tz[j] = tp[2 * NTGT + t];
        tt[j] = __fadd_rn(__fadd_rn(__fmul_rn(tx[j], tx[j]),
                                    __fmul_rn(ty[j], ty[j])),
                          __fmul_rn(tz[j], tz[j]));
    }

    __syncthreads();

    int lbase = wave * STRIPE;              // this wave's stripe in the chunk
    int gbase = cg + lbase;                 // global source index base (uniform)
    float best[TPL];
    int bi[TPL];
#pragma unroll
    for (int j = 0; j < TPL; ++j) { best[j] = FLT_MAX; bi[j] = 0; }

    // depth-1 register pipeline over LDS, groups of 4 sources. The final
    // prefetch over-reads ls[lbase+STRIPE .. +STRIPE+3] (in-bounds of the
    // 1024-entry array, values never consumed).
    float4 cur[4], nxt[4];
#pragma unroll
    for (int k = 0; k < 4; ++k) cur[k] = ls[lbase + k];

#pragma unroll 4
    for (int i0 = 0; i0 < STRIPE; i0 += 4) {
#pragma unroll
        for (int k = 0; k < 4; ++k) nxt[k] = ls[lbase + i0 + 4 + k];
#pragma unroll
        for (int k = 0; k < 4; ++k) {
            float4 f = cur[k];
            int cand = gbase + i0 + k;
#pragma unroll
            for (int j = 0; j < TPL; ++j) {
                float acc = __fmul_rn(tx[j], f.x);
                acc = __fmaf_rn(ty[j], f.y, acc);
                acc = __fmaf_rn(tz[j], f.z, acc);
                float d2 = __fmaf_rn(-2.0f, acc, __fadd_rn(tt[j], f.w));
                if (d2 < best[j]) { best[j] = d2; bi[j] = cand; }  // strict '<'
            }
        }
#pragma unroll
        for (int k = 0; k < 4; ++k) cur[k] = nxt[k];
    }

    __syncthreads();                        // done READING ls before aliasing

    // cross-wave combine in LDS (waves cover ascending source stripes, so
    // ascending-w scan with strict-less + tie->lower-index == np.argmin).
    float* smin = (float*)ls;
    int* sidx = (int*)(smin + WAVES * TGT_PER_BLOCK);
#pragma unroll
    for (int j = 0; j < TPL; ++j) {
        smin[wave * TGT_PER_BLOCK + 64 * j + lane] = best[j];
        sidx[wave * TGT_PER_BLOCK + 64 * j + lane] = bi[j];
    }
    __syncthreads();

#pragma unroll
    for (int r = 0; r < TGT_PER_BLOCK / THREADS; ++r) {
        int t = r * THREADS + tid;
        float m = smin[t];
        int mi = sidx[t];
#pragma unroll
        for (int w = 1; w < WAVES; ++w) {
            float mj = smin[w * TGT_PER_BLOCK + t];
            int ij = sidx[w * TGT_PER_BLOCK + t];
            if (mj < m || (mj == m && ij < mi)) { m = mj; mi = ij; }
        }
        // total-order map: monotone wrt float '<' (handles negatives); the
        // packed u64 compares lexicographically as (d2, first index).
        unsigned u = __float_as_uint(m);
        unsigned ord = (u & 0x80000000u) ? ~u : (u | 0x80000000u);
        part[((size_t)b * SPLITS + split) * NTGT + tbase + t] =
            ((unsigned long long)ord << 32) | (unsigned)mi;
    }
}

// ---------------------------------------------------------------------------
// gate_kernel<SPLITS>: combine split-partials (plain u64 '<' min ==
// lexicographic (d2, first-index), bit-identical winner across ascending
// splits), then the verified 16-way strided max over sem_logits + sigmoid.
// ---------------------------------------------------------------------------
template <int SPLITS>
__global__ __launch_bounds__(256) void gate_kernel(
    const unsigned long long* __restrict__ part,  // [B][SPLITS][NTGT]
    const float* __restrict__ sem_logits,         // [B, K, NS]
    float* __restrict__ out)                      // [B*NT]
{
    int gt = blockIdx.x * 256 + threadIdx.x;      // 0 .. B*NT-1
    int b = gt >> 14;                             // NTGT == 16384
    int t = gt & (NTGT - 1);

    const unsigned long long* pp = part + (size_t)b * SPLITS * NTGT + t;
    unsigned long long best = pp[0];
#pragma unroll
    for (int s = 1; s < SPLITS; ++s) {
        unsigned long long v = pp[(size_t)s * NTGT];  // coalesced in t
        if (v < best) best = v;
    }
    int mi = (int)(best & 0xFFFFFFFFull);

    const float* lg = sem_logits + (size_t)b * KCLS * NSRC + mi;
    float mm = lg[0];
#pragma unroll
    for (int k = 1; k < KCLS; ++k) mm = fmaxf(mm, lg[(size_t)k * NSRC]);
    out[gt] = 1.0f / (1.0f + expf(-mm));
}

extern "C" void kernel_launch(void* const* d_in, const int* in_sizes, int n_in,
                              void* d_out, int out_size, void* d_ws, size_t ws_size,
                              hipStream_t stream) {
    const float* sem_logits = (const float*)d_in[0];   // [B,K,NS] fp32
    const float* source_pos = (const float*)d_in[1];   // [B,3,NS] fp32
    const float* target_pos = (const float*)d_in[2];   // [B,3,NT] fp32
    float* out = (float*)d_out;                        // [B,NT,1] fp32

    unsigned long long* part = (unsigned long long*)d_ws;

    const size_t need16 = (size_t)BATCH * 16 * NTGT * 8;   // 8 MB
    if (ws_size >= need16) {
        nn_kernel<16><<<BATCH * (NTGT / TGT_PER_BLOCK) * 16, THREADS, 0, stream>>>(
            source_pos, target_pos, part);
        gate_kernel<16><<<(BATCH * NTGT) / 256, 256, 0, stream>>>(
            part, sem_logits, out);
    } else {
        // fallback: 4 MB partials (R1-proven workspace size)
        nn_kernel<8><<<BATCH * (NTGT / TGT_PER_BLOCK) * 8, THREADS, 0, stream>>>(
            source_pos, target_pos, part);
        gate_kernel<8><<<(BATCH * NTGT) / 256, 256, 0, stream>>>(
            part, sem_logits, out);
    }
}